// Round 1
// baseline (557.468 us; speedup 1.0000x reference)
//
#include <hip/hip_runtime.h>
#include <hip/hip_bf16.h>
#include <stdint.h>

// ---------------------------------------------------------------------------
// STE ternary linear: out = x @ q^T, q = ternary(weight, thr=0.05*mean|w|)
// x: [8192, 4096] fp32, weight: [4096, 4096] fp32, out: [8192, 4096] fp32
// Plan: fp64 abs-mean reduce -> ternary quantize to bf16 bits -> x to bf16
//       -> m97-style bf16 MFMA GEMM (B^T layout), fp32 accumulate.
// ---------------------------------------------------------------------------

typedef __attribute__((ext_vector_type(8))) __bf16 bf16x8;   // 4 VGPRs
typedef __attribute__((ext_vector_type(4))) float  f32x4;    // 4 AGPRs

#define BM 128
#define BN 128
#define BK 32

__device__ inline void gld_lds16(const void* g, void* l) {
  // 16B per lane, LDS dest = wave-uniform base + lane*16
  __builtin_amdgcn_global_load_lds(
      (__attribute__((address_space(1))) void*)g,
      (__attribute__((address_space(3))) void*)l,
      16, 0, 0);
}

// ---------------- abs-mean reduction (fp64 accumulate) ----------------------
__global__ void absmean_kernel(const float4* __restrict__ w,
                               double* __restrict__ out, int n4) {
  double s = 0.0;
  int stride = gridDim.x * blockDim.x;
  for (int i = blockIdx.x * blockDim.x + threadIdx.x; i < n4; i += stride) {
    float4 v = w[i];
    s += (double)(fabsf(v.x) + fabsf(v.y)) + (double)(fabsf(v.z) + fabsf(v.w));
  }
#pragma unroll
  for (int off = 32; off > 0; off >>= 1) s += __shfl_down(s, off, 64);
  __shared__ double wsum[4];
  int lane = threadIdx.x & 63, wave = threadIdx.x >> 6;
  if (lane == 0) wsum[wave] = s;
  __syncthreads();
  if (threadIdx.x == 0) {
    double t = wsum[0] + wsum[1] + wsum[2] + wsum[3];
    atomicAdd(out, t);
  }
}

// ---------------- ternary quantize weight -> bf16 bits ----------------------
__global__ void quant_kernel(const float4* __restrict__ w,
                             const double* __restrict__ sum,
                             ushort4* __restrict__ q, int n4, double inv_n) {
  const float thr = (float)(0.05 * (*sum) * inv_n);
  int stride = gridDim.x * blockDim.x;
  for (int i = blockIdx.x * blockDim.x + threadIdx.x; i < n4; i += stride) {
    float4 v = w[i];
    ushort4 o;
    o.x = v.x > thr ? 0x3F80u : (v.x < -thr ? 0xBF80u : 0u);
    o.y = v.y > thr ? 0x3F80u : (v.y < -thr ? 0xBF80u : 0u);
    o.z = v.z > thr ? 0x3F80u : (v.z < -thr ? 0xBF80u : 0u);
    o.w = v.w > thr ? 0x3F80u : (v.w < -thr ? 0xBF80u : 0u);
    q[i] = o;
  }
}

// ---------------- x fp32 -> bf16 (RNE) --------------------------------------
__device__ inline unsigned short f2bf_rne(float f) {
  union { float f; uint32_t u; } c; c.f = f;
  uint32_t u = c.u;
  return (unsigned short)((u + 0x7FFFu + ((u >> 16) & 1u)) >> 16);
}

__global__ void cvt_kernel(const float4* __restrict__ x,
                           ushort4* __restrict__ xb, int n4) {
  int stride = gridDim.x * blockDim.x;
  for (int i = blockIdx.x * blockDim.x + threadIdx.x; i < n4; i += stride) {
    float4 v = x[i];
    ushort4 o;
    o.x = f2bf_rne(v.x);
    o.y = f2bf_rne(v.y);
    o.z = f2bf_rne(v.z);
    o.w = f2bf_rne(v.w);
    xb[i] = o;
  }
}

// ---------------- bf16 GEMM, B^T layout (m97 structure) ---------------------
// A: [M][K] bf16 bits, B: [N][K] bf16 bits, C: [M][N] fp32
// block = 256 threads = 4 waves (2x2), each wave 64x64 out via 4x4 MFMA tiles
__global__ __launch_bounds__(256, 2) void gemm_bt(
    const unsigned short* __restrict__ A,
    const unsigned short* __restrict__ B,
    float* __restrict__ C, int M, int N, int K) {
  __shared__ unsigned short As[BM * BK];  // 8 KiB
  __shared__ unsigned short Bs[BN * BK];  // 8 KiB

  const int tid = threadIdx.x;
  const int lane = tid & 63;
  const int wave = tid >> 6;

  const int bm = blockIdx.y * BM;
  const int bn = blockIdx.x * BN;

  // staging: 8 chunks of 1024B per tile; wave handles chunks 2w, 2w+1.
  // chunk c covers rows [16c, 16c+16), lane l -> row 16c + l/4, k (l%4)*8
  const int ca0 = wave * 2;
  const int ca1 = wave * 2 + 1;
  const int rl = lane >> 2;
  const int kl = (lane & 3) * 8;

  const unsigned short* a0 = A + (size_t)(bm + ca0 * 16 + rl) * K + kl;
  const unsigned short* a1 = A + (size_t)(bm + ca1 * 16 + rl) * K + kl;
  const unsigned short* b0 = B + (size_t)(bn + ca0 * 16 + rl) * K + kl;
  const unsigned short* b1 = B + (size_t)(bn + ca1 * 16 + rl) * K + kl;

  unsigned short* la0 = &As[ca0 * 512];
  unsigned short* la1 = &As[ca1 * 512];
  unsigned short* lb0 = &Bs[ca0 * 512];
  unsigned short* lb1 = &Bs[ca1 * 512];

  const int wm = (wave >> 1) * 64;  // wave 2x2 grid over 128x128
  const int wn = (wave & 1) * 64;

  const int fr = lane & 15;        // fragment row (m or n within 16-tile)
  const int fk = (lane >> 4) * 8;  // fragment k offset

  f32x4 acc[4][4] = {};

  for (int k0 = 0; k0 < K; k0 += BK) {
    gld_lds16(a0 + k0, la0);
    gld_lds16(a1 + k0, la1);
    gld_lds16(b0 + k0, lb0);
    gld_lds16(b1 + k0, lb1);
    __syncthreads();  // drains vmcnt before barrier (compiler-inserted)

    bf16x8 af[4], bfr[4];
#pragma unroll
    for (int i = 0; i < 4; ++i) {
      af[i]  = *(const bf16x8*)(&As[(wm + i * 16 + fr) * BK + fk]);
      bfr[i] = *(const bf16x8*)(&Bs[(wn + i * 16 + fr) * BK + fk]);
    }
#pragma unroll
    for (int mi = 0; mi < 4; ++mi)
#pragma unroll
      for (int ni = 0; ni < 4; ++ni)
        acc[mi][ni] = __builtin_amdgcn_mfma_f32_16x16x32_bf16(
            af[mi], bfr[ni], acc[mi][ni], 0, 0, 0);
    __syncthreads();
  }

  // epilogue: D row = (lane>>4)*4 + r, col = lane&15  [m89/m91 verified]
  const int cn = lane & 15;
  const int cm = (lane >> 4) * 4;
#pragma unroll
  for (int mi = 0; mi < 4; ++mi) {
#pragma unroll
    for (int ni = 0; ni < 4; ++ni) {
#pragma unroll
      for (int r = 0; r < 4; ++r) {
        int m = bm + wm + mi * 16 + cm + r;
        int n = bn + wn + ni * 16 + cn;
        C[(size_t)m * N + n] = acc[mi][ni][r];
      }
    }
  }
}

// ---------------------------------------------------------------------------
extern "C" void kernel_launch(void* const* d_in, const int* in_sizes, int n_in,
                              void* d_out, int out_size, void* d_ws,
                              size_t ws_size, hipStream_t stream) {
  const float* x = (const float*)d_in[0];
  const float* w = (const float*)d_in[1];
  float* out = (float*)d_out;

  const int K = 4096;
  const int N = 4096;
  const int M = in_sizes[0] / K;   // 8192
  const int NW = in_sizes[1];      // 4096*4096

  char* ws = (char*)d_ws;
  double* d_sum = (double*)ws;                                   // 8 B
  unsigned short* qb = (unsigned short*)(ws + 256);               // N*K*2
  unsigned short* xb = (unsigned short*)(ws + 256 + (size_t)N * K * 2);

  hipMemsetAsync(d_sum, 0, sizeof(double), stream);
  absmean_kernel<<<512, 256, 0, stream>>>((const float4*)w, d_sum, NW / 4);
  quant_kernel<<<1024, 256, 0, stream>>>((const float4*)w, d_sum,
                                         (ushort4*)qb, NW / 4, 1.0 / NW);
  cvt_kernel<<<1024, 256, 0, stream>>>((const float4*)x, (ushort4*)xb,
                                       in_sizes[0] / 4);
  dim3 grid(N / BN, M / BM);
  gemm_bt<<<grid, 256, 0, stream>>>(xb, qb, out, M, N, K);
}